// Round 5
// baseline (1971.977 us; speedup 1.0000x reference)
//
#include <hip/hip_runtime.h>

#define S_LEN  1024
#define D_KK   64
#define N_HEAD 96   // B*H = 8*12
#define BQ     16   // q-rows per block
#define TK     128  // K rows per QK tile
#define NT_QK  (S_LEN / TK)   // 8 QK tiles
#define CHK    128            // PV k-chunk
#define NCH    (S_LEN / CHK)  // 8 PV chunks
#define KSTR   129            // phase1 K^T LDS stride (floats)
#define QSTR   68             // phase1 Q LDS stride (floats)
#define VSTR   68             // phase2 V LDS stride (floats)
#define PSTR   136            // phase2 P row stride (floats; 128 + 8, 16B aligned)

// Fused: scores + mask + softmax + attn-write + context, one kernel.
// block = 256 threads (4 waves); 16 q-rows/block, 4 rows/wave.
// Lane l holds probabilities for k = l + 64*j, j = 0..15 (full row in 64 VGPRs).
//
// Occupancy is pinned at ~8 waves/CU for any VGPR in (64,256] (rounds 2-4
// evidence) -> registers up to ~256 are FREE. launch_bounds(256,1) lifts the
// allocator cap (with (256,2) the compiler capped at 128 and spilled acc[]:
// round 4's WRITE_SIZE showed +2.5GB scratch traffic).
//
// LDS = 43,520 B:
//   smA: ph1 K^T [64][129] (33,024B) | ph2 V chunk [128][68] (34,816B) | epilogue red (16KB)
//   smB: ph1 Q   [16][68]            | ph2 P [16 rows][136]   (8,704B)
__global__ __launch_bounds__(256, 1) void attn_fused_kernel(
    const float* __restrict__ Qg, const float* __restrict__ Kg,
    const float* __restrict__ Vg, const int* __restrict__ maskg,
    float* __restrict__ attng, float* __restrict__ ctxg)
{
    __shared__ __align__(16) float smA[CHK * VSTR];   // 8704 floats = 34,816 B (>= 64*129)
    __shared__ __align__(16) float smB[BQ * PSTR];    // 2176 floats =  8,704 B (>= 16*68)

    const int t     = threadIdx.x;
    const int lane  = t & 63;
    const int wave  = t >> 6;
    const int head  = blockIdx.y;
    const int q0    = blockIdx.x * BQ;
    const int rbase = wave << 2;

    // ---- stage Q tile (16 x 64), coalesced float4 ----
    {
        const int r  = t >> 4;
        const int d0 = (t & 15) << 2;
        const float4 qv = *(const float4*)(Qg + ((size_t)head * S_LEN + q0 + r) * D_KK + d0);
        smB[r * QSTR + d0 + 0] = qv.x;
        smB[r * QSTR + d0 + 1] = qv.y;
        smB[r * QSTR + d0 + 2] = qv.z;
        smB[r * QSTR + d0 + 3] = qv.w;
    }

    float s[4][16];
    #pragma unroll
    for (int r = 0; r < 4; ++r)
        #pragma unroll
        for (int j = 0; j < 16; ++j) s[r][j] = 0.f;

    // ---- Phase 1: scores = Q K^T (verified structure, unchanged) ----
    #pragma unroll
    for (int kt_i = 0; kt_i < NT_QK; ++kt_i) {
        __syncthreads();
        {
            const int d0 = (t & 15) << 2;
            const int kb = t >> 4;
            #pragma unroll
            for (int c = 0; c < TK / 16; ++c) {
                const int kl = c * 16 + kb;
                const float4 kv = *(const float4*)(Kg + ((size_t)head * S_LEN + kt_i * TK + kl) * D_KK + d0);
                smA[(d0 + 0) * KSTR + kl] = kv.x;
                smA[(d0 + 1) * KSTR + kl] = kv.y;
                smA[(d0 + 2) * KSTR + kl] = kv.z;
                smA[(d0 + 3) * KSTR + kl] = kv.w;
            }
        }
        __syncthreads();

        #pragma unroll
        for (int d0 = 0; d0 < D_KK; d0 += 4) {
            float4 qv[4];
            #pragma unroll
            for (int r = 0; r < 4; ++r)
                qv[r] = *(const float4*)(&smB[(rbase + r) * QSTR + d0]);  // broadcast
            #pragma unroll
            for (int dd = 0; dd < 4; ++dd) {
                const float k0v = smA[(d0 + dd) * KSTR + lane];           // 2-way (free)
                const float k1v = smA[(d0 + dd) * KSTR + lane + 64];
                #pragma unroll
                for (int r = 0; r < 4; ++r) {
                    const float qd = (&qv[r].x)[dd];
                    s[r][2 * kt_i + 0] = fmaf(qd, k0v, s[r][2 * kt_i + 0]);
                    s[r][2 * kt_i + 1] = fmaf(qd, k1v, s[r][2 * kt_i + 1]);
                }
            }
        }
    }

    // ---- mask + softmax + attn write (unchanged) ----
    #pragma unroll
    for (int r = 0; r < 4; ++r) {
        const int q = q0 + rbase + r;
        const int*  mrow = maskg + ((size_t)head * S_LEN + q) * S_LEN;
        float*      arow = attng + ((size_t)head * S_LEN + q) * S_LEN;
        float m = -3.0e38f;
        #pragma unroll
        for (int j = 0; j < 16; ++j) {
            const int mk = __builtin_nontemporal_load(&mrow[lane + 64 * j]);
            float v = s[r][j] * 0.125f;                   // * 1/sqrt(64)
            if (mk) v = -1.0e9f;
            s[r][j] = v;
            m = fmaxf(m, v);
        }
        #pragma unroll
        for (int off = 32; off >= 1; off >>= 1)
            m = fmaxf(m, __shfl_xor(m, off, 64));
        float l = 0.0f;
        #pragma unroll
        for (int j = 0; j < 16; ++j) {
            s[r][j] = __expf(s[r][j] - m);
            l += s[r][j];
        }
        #pragma unroll
        for (int off = 32; off >= 1; off >>= 1)
            l += __shfl_xor(l, off, 64);
        const float inv = 1.0f / l;
        #pragma unroll
        for (int j = 0; j < 16; ++j) {
            s[r][j] *= inv;                                // s[] now = attn probs
            __builtin_nontemporal_store(s[r][j], &arow[lane + 64 * j]);
        }
    }

    // ---- Phase 2: context = P @ V, k-partitioned partial sums ----
    // Thread (tk = t>>4, td = t&15) owns k-rows [8tk,8tk+8) of each chunk,
    // d-cols [4td,4td+4), ALL 16 q-rows -> acc[16][4] (64 "free" VGPRs).
    // V read from LDS exactly once per block; P reads broadcast-16.
    const int tk = t >> 4;
    const int td = t & 15;

    float acc[16][4];
    #pragma unroll
    for (int r = 0; r < 16; ++r)
        #pragma unroll
        for (int d = 0; d < 4; ++d) acc[r][d] = 0.f;

    #pragma unroll                   // MUST unroll: s[r][2c] needs static index
    for (int c = 0; c < NCH; ++c) {
        __syncthreads();             // prev chunk's (or phase-1) smA/smB readers done
        // stage V chunk 128 x 64 (coalesced float4; contiguous 256B rows in LDS)
        #pragma unroll
        for (int p_ = 0; p_ < 8; ++p_) {
            const int i  = t + 256 * p_;
            const int k  = i >> 4;
            const int d0 = (i & 15) << 2;
            const float4 v = *(const float4*)(Vg + ((size_t)head * S_LEN + c * CHK + k) * D_KK + d0);
            *(float4*)(&smA[k * VSTR + d0]) = v;
        }
        // dump P rows (own rows only): P[rbase+r][k], k-local = lane, 64+lane
        // write addrs consecutive in lane -> conflict-free
        #pragma unroll
        for (int r = 0; r < 4; ++r) {
            smB[(rbase + r) * PSTR + lane]      = s[r][2 * c + 0];
            smB[(rbase + r) * PSTR + 64 + lane] = s[r][2 * c + 1];
        }
        __syncthreads();             // V chunk + P visible

        #pragma unroll
        for (int e = 0; e < 2; ++e) {
            float4 v4[4];
            #pragma unroll
            for (int i = 0; i < 4; ++i)    // 16-lane groups read 256B contig: conflict-free
                v4[i] = *(const float4*)(&smA[(8 * tk + 4 * e + i) * VSTR + (td << 2)]);
            #pragma unroll
            for (int r = 0; r < 16; ++r) {
                // 4 probs for this thread's k's: bcast-16, 4 distinct bank-groups
                const float4 p4 = *(const float4*)(&smB[r * PSTR + 8 * tk + 4 * e]);
                #pragma unroll
                for (int i = 0; i < 4; ++i) {
                    const float p = (&p4.x)[i];
                    acc[r][0] = fmaf(p, v4[i].x, acc[r][0]);
                    acc[r][1] = fmaf(p, v4[i].y, acc[r][1]);
                    acc[r][2] = fmaf(p, v4[i].z, acc[r][2]);
                    acc[r][3] = fmaf(p, v4[i].w, acc[r][3]);
                }
            }
        }
    }

    // ---- k-reduction: 16 tk-groups -> 1 ----
    // (a) within wave: lanes {l, l^16, l^32, l^48} share td -> butterfly
    #pragma unroll
    for (int r = 0; r < 16; ++r)
        #pragma unroll
        for (int d = 0; d < 4; ++d) {
            acc[r][d] += __shfl_xor(acc[r][d], 16, 64);
            acc[r][d] += __shfl_xor(acc[r][d], 32, 64);
        }
    // (b) across waves via LDS: red[w][r][td] float4s at smA (V dead now)
    __syncthreads();                 // all smA V-reads complete
    {
        const int qg  = lane >> 4;   // quarter writes rows 4qg..4qg+3
        const int tdw = lane & 15;
        #pragma unroll
        for (int rr = 0; rr < 4; ++rr) {
            const int r = 4 * qg + rr;
            float4 a; a.x = acc[r][0]; a.y = acc[r][1]; a.z = acc[r][2]; a.w = acc[r][3];
            *(float4*)(&smA[(wave * 256 + r * 16 + tdw) * 4]) = a;
        }
    }
    __syncthreads();
    {
        // thread t -> output row (t>>4), cols 4*(t&15)..: read idx w*256 + t (contiguous)
        float4 o = *(const float4*)(&smA[(0 * 256 + t) * 4]);
        #pragma unroll
        for (int w = 1; w < 4; ++w) {
            const float4 p = *(const float4*)(&smA[(w * 256 + t) * 4]);
            o.x += p.x; o.y += p.y; o.z += p.z; o.w += p.w;
        }
        *(float4*)(ctxg + ((size_t)head * S_LEN + q0 + (t >> 4)) * D_KK + ((t & 15) << 2)) = o;
    }
}

extern "C" void kernel_launch(void* const* d_in, const int* in_sizes, int n_in,
                              void* d_out, int out_size, void* d_ws, size_t ws_size,
                              hipStream_t stream) {
    const float* Q    = (const float*)d_in[0];
    const float* K    = (const float*)d_in[1];
    const float* V    = (const float*)d_in[2];
    const int*   mask = (const int*)d_in[3];

    float* ctx  = (float*)d_out;                                // [B,H,S,D] first
    float* attn = ctx + (size_t)N_HEAD * S_LEN * D_KK;          // then [B,H,S,S]

    dim3 grid(S_LEN / BQ, N_HEAD);
    attn_fused_kernel<<<grid, 256, 0, stream>>>(Q, K, V, mask, attn, ctx);
}

// Round 6
// 1112.932 us; speedup vs baseline: 1.7719x; 1.7719x over previous
//
#include <hip/hip_runtime.h>

#define S_LEN  1024
#define D_KK   64
#define N_HEAD 96   // B*H = 8*12
#define BQ     16   // q-rows per block
#define TK     128  // K rows per QK tile
#define NT_QK  (S_LEN / TK)   // 8 QK tiles
#define CHK    128            // PV k-chunk
#define NCH    (S_LEN / CHK)  // 8 PV chunks
#define KSTR   129            // phase1 K^T LDS stride (floats)
#define QSTR   68             // phase1 Q LDS stride (floats)
#define VSTR   68             // phase2 V LDS stride (floats)
#define PSTR   152            // phase2 P row stride (floats; 128 + swizzle room, 608B = 16B-aligned)

// Fused: scores + mask + softmax + attn-write + context, one kernel.
// block = 256 threads (4 waves); 16 q-rows/block, 4 rows/wave.
// Lane l holds probabilities for k = l + 64*j, j = 0..15 (full row in 64 VGPRs).
//
// HARD CONSTRAINT (rounds 1/4/5 evidence): register budget is 128.
//   (256,2) -> cap 128, no spill at <=128 live; (256,1) -> allocator spills
//   AND scratch halves occupancy; acc[16][4] (r4) -> 2.5GB scratch traffic.
// Phase 2 is sized to fit: acc[4][4] (16 regs), k-split 4 ways across lanes.
//
// LDS = 44,544 B (2 blocks/CU; occupancy is VGPR-pinned at 8 waves/CU anyway):
//   smA: ph1 K^T [64][129] (33,024B) | ph2 V chunk [128][68] (34,816B)
//   smB: ph1 Q   [16][68]            | ph2 P [16 rows][152]   (9,728B)
//        (wave dumps/reads only its OWN 4 P-rows -> no cross-wave hazard)
__global__ __launch_bounds__(256, 2) void attn_fused_kernel(
    const float* __restrict__ Qg, const float* __restrict__ Kg,
    const float* __restrict__ Vg, const int* __restrict__ maskg,
    float* __restrict__ attng, float* __restrict__ ctxg)
{
    __shared__ __align__(16) float smA[CHK * VSTR];   // 8704 floats = 34,816 B (>= 64*129)
    __shared__ __align__(16) float smB[BQ * PSTR];    // 2432 floats =  9,728 B (>= 16*68)

    const int t     = threadIdx.x;
    const int lane  = t & 63;
    const int wave  = t >> 6;
    const int head  = blockIdx.y;
    const int q0    = blockIdx.x * BQ;
    const int rbase = wave << 2;

    // ---- stage Q tile (16 x 64), coalesced float4 ----
    {
        const int r  = t >> 4;
        const int d0 = (t & 15) << 2;
        const float4 qv = *(const float4*)(Qg + ((size_t)head * S_LEN + q0 + r) * D_KK + d0);
        smB[r * QSTR + d0 + 0] = qv.x;
        smB[r * QSTR + d0 + 1] = qv.y;
        smB[r * QSTR + d0 + 2] = qv.z;
        smB[r * QSTR + d0 + 3] = qv.w;
    }

    float s[4][16];
    #pragma unroll
    for (int r = 0; r < 4; ++r)
        #pragma unroll
        for (int j = 0; j < 16; ++j) s[r][j] = 0.f;

    // ---- Phase 1: scores = Q K^T (verified 737us structure, unchanged) ----
    #pragma unroll
    for (int kt_i = 0; kt_i < NT_QK; ++kt_i) {
        __syncthreads();
        {
            const int d0 = (t & 15) << 2;
            const int kb = t >> 4;
            #pragma unroll
            for (int c = 0; c < TK / 16; ++c) {
                const int kl = c * 16 + kb;
                const float4 kv = *(const float4*)(Kg + ((size_t)head * S_LEN + kt_i * TK + kl) * D_KK + d0);
                smA[(d0 + 0) * KSTR + kl] = kv.x;
                smA[(d0 + 1) * KSTR + kl] = kv.y;
                smA[(d0 + 2) * KSTR + kl] = kv.z;
                smA[(d0 + 3) * KSTR + kl] = kv.w;
            }
        }
        __syncthreads();

        #pragma unroll
        for (int d0 = 0; d0 < D_KK; d0 += 4) {
            float4 qv[4];
            #pragma unroll
            for (int r = 0; r < 4; ++r)
                qv[r] = *(const float4*)(&smB[(rbase + r) * QSTR + d0]);  // broadcast
            #pragma unroll
            for (int dd = 0; dd < 4; ++dd) {
                const float k0v = smA[(d0 + dd) * KSTR + lane];           // 2-way (free)
                const float k1v = smA[(d0 + dd) * KSTR + lane + 64];
                #pragma unroll
                for (int r = 0; r < 4; ++r) {
                    const float qd = (&qv[r].x)[dd];
                    s[r][2 * kt_i + 0] = fmaf(qd, k0v, s[r][2 * kt_i + 0]);
                    s[r][2 * kt_i + 1] = fmaf(qd, k1v, s[r][2 * kt_i + 1]);
                }
            }
        }
    }

    // ---- mask + softmax + attn write (unchanged) ----
    #pragma unroll
    for (int r = 0; r < 4; ++r) {
        const int q = q0 + rbase + r;
        const int*  mrow = maskg + ((size_t)head * S_LEN + q) * S_LEN;
        float*      arow = attng + ((size_t)head * S_LEN + q) * S_LEN;
        float m = -3.0e38f;
        #pragma unroll
        for (int j = 0; j < 16; ++j) {
            const int mk = __builtin_nontemporal_load(&mrow[lane + 64 * j]);
            float v = s[r][j] * 0.125f;                   // * 1/sqrt(64)
            if (mk) v = -1.0e9f;
            s[r][j] = v;
            m = fmaxf(m, v);
        }
        #pragma unroll
        for (int off = 32; off >= 1; off >>= 1)
            m = fmaxf(m, __shfl_xor(m, off, 64));
        float l = 0.0f;
        #pragma unroll
        for (int j = 0; j < 16; ++j) {
            s[r][j] = __expf(s[r][j] - m);
            l += s[r][j];
        }
        #pragma unroll
        for (int off = 32; off >= 1; off >>= 1)
            l += __shfl_xor(l, off, 64);
        const float inv = 1.0f / l;
        #pragma unroll
        for (int j = 0; j < 16; ++j) {
            s[r][j] *= inv;                                // s[] now = attn probs
            __builtin_nontemporal_store(s[r][j], &arow[lane + 64 * j]);
        }
    }

    // ---- Phase 2: context = P @ V, lane-level k-split ----
    // lane = tk*16 + td: owns k-quarter [32tk,32tk+32) of each chunk,
    // d-cols [4td,4td+4), its wave's 4 q-rows -> acc[4][4] (16 regs).
    // LDS reads/chunk/lane: 32 V-b128 + 32 P-b128 (vs 160 in the r2 scheme).
    const int tk = lane >> 4;
    const int td = lane & 15;

    float acc[4][4] = {{0.f,0.f,0.f,0.f},{0.f,0.f,0.f,0.f},
                       {0.f,0.f,0.f,0.f},{0.f,0.f,0.f,0.f}};

    #pragma unroll                   // MUST unroll: s[r][2c] needs static index
    for (int c = 0; c < NCH; ++c) {
        __syncthreads();             // prev chunk's (or phase-1) smA readers done
        // stage V chunk 128 x 64 (coalesced float4; conflict-free writes)
        #pragma unroll
        for (int p_ = 0; p_ < 8; ++p_) {
            const int i  = t + 256 * p_;
            const int k  = i >> 4;
            const int d0 = (i & 15) << 2;
            const float4 v = *(const float4*)(Vg + ((size_t)head * S_LEN + c * CHK + k) * D_KK + d0);
            *(float4*)(&smA[k * VSTR + d0]) = v;
        }
        // dump P rows (own rows only), swizzled col' = col + 8*(col>>5)
        // so the 4 tk-groups' b128 reads land on distinct bank-quads.
        {
            const int c0 = lane + 8 * (lane >> 5);            // col'(lane)
            const int c1 = 80 + lane + 8 * (lane >> 5);       // col'(64+lane)
            #pragma unroll
            for (int r = 0; r < 4; ++r) {
                smB[(rbase + r) * PSTR + c0] = s[r][2 * c + 0];
                smB[(rbase + r) * PSTR + c1] = s[r][2 * c + 1];
            }
        }
        __syncthreads();             // V chunk visible (P is same-wave: program order)

        #pragma unroll
        for (int kp = 0; kp < 8; ++kp) {
            const int pc = 40 * tk + 4 * kp;                  // col'(32tk+4kp)
            float4 p4[4];
            #pragma unroll
            for (int r = 0; r < 4; ++r)                       // bcast-16, banks 8*tk apart
                p4[r] = *(const float4*)(&smB[(rbase + r) * PSTR + pc]);
            #pragma unroll
            for (int e = 0; e < 4; ++e) {
                const int k = 32 * tk + 4 * kp + e;
                const float4 v = *(const float4*)(&smA[k * VSTR + (td << 2)]); // dense, free
                #pragma unroll
                for (int r = 0; r < 4; ++r) {
                    const float p = (&p4[r].x)[e];
                    acc[r][0] = fmaf(p, v.x, acc[r][0]);
                    acc[r][1] = fmaf(p, v.y, acc[r][1]);
                    acc[r][2] = fmaf(p, v.z, acc[r][2]);
                    acc[r][3] = fmaf(p, v.w, acc[r][3]);
                }
            }
        }
    }

    // ---- k-reduction over the 4 tk-groups: lanes {l, l^16, l^32, l^48} ----
    #pragma unroll
    for (int r = 0; r < 4; ++r)
        #pragma unroll
        for (int d = 0; d < 4; ++d) {
            acc[r][d] += __shfl_xor(acc[r][d], 16, 64);
            acc[r][d] += __shfl_xor(acc[r][d], 32, 64);
        }
    if (lane < 16) {                 // tk==0 lanes hold the full sum
        #pragma unroll
        for (int r = 0; r < 4; ++r) {
            float4 o;
            o.x = acc[r][0]; o.y = acc[r][1]; o.z = acc[r][2]; o.w = acc[r][3];
            *(float4*)(ctxg + ((size_t)head * S_LEN + q0 + rbase + r) * D_KK + (td << 2)) = o;
        }
    }
}

extern "C" void kernel_launch(void* const* d_in, const int* in_sizes, int n_in,
                              void* d_out, int out_size, void* d_ws, size_t ws_size,
                              hipStream_t stream) {
    const float* Q    = (const float*)d_in[0];
    const float* K    = (const float*)d_in[1];
    const float* V    = (const float*)d_in[2];
    const int*   mask = (const int*)d_in[3];

    float* ctx  = (float*)d_out;                                // [B,H,S,D] first
    float* attn = ctx + (size_t)N_HEAD * S_LEN * D_KK;          // then [B,H,S,S]

    dim3 grid(S_LEN / BQ, N_HEAD);
    attn_fused_kernel<<<grid, 256, 0, stream>>>(Q, K, V, mask, attn, ctx);
}